// Round 1
// baseline (951.423 us; speedup 1.0000x reference)
//
#include <hip/hip_runtime.h>
#include <hip/hip_bf16.h>

constexpr int BB = 4096;   // batch
constexpr int TT = 2048;   // time
constexpr int HH = 32;     // hidden

// ---------- fast math (v_exp_f32 / v_rcp_f32) ----------
__device__ __forceinline__ float fexp2(float x) { return __builtin_amdgcn_exp2f(x); }
__device__ __forceinline__ float frcp(float x)  { return __builtin_amdgcn_rcpf(x); }
__device__ __forceinline__ float fsigmoid(float x) {
    // 1/(1+e^-x) = rcp(1 + 2^(-x*log2e))
    return frcp(1.0f + fexp2(x * -1.4426950408889634f));
}
__device__ __forceinline__ float ftanh(float x) {
    // tanh(x) = 1 - 2/(e^(2x)+1)
    return 1.0f - 2.0f * frcp(1.0f + fexp2(x * 2.8853900817779268f));
}
__device__ __forceinline__ float felu(float x) {
    return x > 0.0f ? x : (fexp2(x * 1.4426950408889634f) - 1.0f);
}

// ---------- kernel 1: counting sort of batch indices by length, descending ----------
// perm[0..B) = batch indices ordered longest-first. Single block, 256 threads.
__global__ void sort_by_len_kernel(const int* __restrict__ lengths, int* __restrict__ perm) {
    __shared__ int hist[TT];     // key = TT - len  in [0, TT-1]
    __shared__ int csum[256];
    const int tid = threadIdx.x;
    for (int i = tid; i < TT; i += 256) hist[i] = 0;
    __syncthreads();
    for (int i = tid; i < BB; i += 256) atomicAdd(&hist[TT - lengths[i]], 1);
    __syncthreads();
    const int base = tid * 8;
    int loc[8];
    int s = 0;
#pragma unroll
    for (int j = 0; j < 8; ++j) { loc[j] = hist[base + j]; s += loc[j]; }
    csum[tid] = s;
    __syncthreads();
    // inclusive scan over 256 chunk sums
    for (int off = 1; off < 256; off <<= 1) {
        int v = (tid >= off) ? csum[tid - off] : 0;
        __syncthreads();
        csum[tid] += v;
        __syncthreads();
    }
    int run = csum[tid] - s;     // exclusive base for this chunk
#pragma unroll
    for (int j = 0; j < 8; ++j) { int t = loc[j]; hist[base + j] = run; run += t; }
    __syncthreads();
    for (int i = tid; i < BB; i += 256) {
        int pos = atomicAdd(&hist[TT - lengths[i]], 1);
        perm[pos] = i;
    }
}

// ---------- kernel 2: backward LSTM + MLP head ----------
// 1 wave per block; 2 batch elements per wave (32 lanes each, lane owns hidden unit n).
// Weights (4 rows x 32) live in VGPRs; h broadcast via double-buffered LDS.
__global__ __launch_bounds__(64, 2)
void lstm_kernel(const float* __restrict__ x, const int* __restrict__ lengths,
                 const float* __restrict__ w_ih, const float* __restrict__ w_hh,
                 const float* __restrict__ b_ih, const float* __restrict__ b_hh,
                 const float* __restrict__ fc_w, const float* __restrict__ fc_b,
                 const float* __restrict__ fc2_w, const float* __restrict__ fc2_b,
                 float* __restrict__ out, const int* __restrict__ perm) {
    __shared__ __align__(16) float hbuf[2][64];
    __shared__ float xbuf[64];

    const int lane = threadIdx.x;       // 0..63
    const int half = lane >> 5;         // which batch slot
    const int n    = lane & 31;         // hidden unit

    const int p = blockIdx.x;
    int b0, b1;
    if (perm) { b0 = perm[2 * p]; b1 = perm[2 * p + 1]; }
    else      { b0 = 2 * p;       b1 = 2 * p + 1; }
    const int L0 = lengths[b0];
    const int L1 = lengths[b1];
    const int b  = half ? b1 : b0;
    const int L  = half ? L1 : L0;
    const int Lmax = max(L0, L1);

    // preload this lane's 4 gate rows (i,f,g,o for unit n) into registers
    float wreg[4][32];
    float wi[4], bias[4];
#pragma unroll
    for (int j = 0; j < 4; ++j) {
        const int r = j * 32 + n;
        wi[j]   = w_ih[r];              // input dim is 1
        bias[j] = b_ih[r] + b_hh[r];
        const float4* wr = reinterpret_cast<const float4*>(w_hh + r * 32);
#pragma unroll
        for (int q = 0; q < 8; ++q) {
            float4 v = wr[q];
            wreg[j][4 * q + 0] = v.x; wreg[j][4 * q + 1] = v.y;
            wreg[j][4 * q + 2] = v.z; wreg[j][4 * q + 3] = v.w;
        }
    }

    float hreg[32];
#pragma unroll
    for (int k = 0; k < 32; ++k) hreg[k] = 0.0f;
    float c = 0.0f;
    const float* xb = x + (size_t)b * TT;

    int t = Lmax - 1;
    while (t >= 0) {
        const int tb = t & ~31;          // stage x[tb..tb+31] for both batches
        __syncthreads();
        xbuf[lane] = xb[tb + n];         // lane == half*32+n; in-bounds since tb+31 <= TT-1
        __syncthreads();
        for (; t >= tb; --t) {
            const float xt = xbuf[(half << 5) | (t - tb)];
            float acc[4];
#pragma unroll
            for (int j = 0; j < 4; ++j) acc[j] = fmaf(wi[j], xt, bias[j]);
#pragma unroll
            for (int k = 0; k < 32; ++k) {
#pragma unroll
                for (int j = 0; j < 4; ++j) acc[j] = fmaf(wreg[j][k], hreg[k], acc[j]);
            }
            const float ig = fsigmoid(acc[0]);
            const float fg = fsigmoid(acc[1]);
            const float gg = ftanh(acc[2]);
            const float og = fsigmoid(acc[3]);
            const bool active = (t < L);           // packed-sequence mask
            const float cn = fmaf(fg, c, ig * gg);
            c = active ? cn : c;
            const float hn = active ? og * ftanh(c) : hreg[n];
            const int par = t & 1;
            hbuf[par][lane] = hn;
            __syncthreads();
            const float4* hp = reinterpret_cast<const float4*>(&hbuf[par][half << 5]);
#pragma unroll
            for (int q = 0; q < 8; ++q) {
                float4 v = hp[q];
                hreg[4 * q + 0] = v.x; hreg[4 * q + 1] = v.y;
                hreg[4 * q + 2] = v.z; hreg[4 * q + 3] = v.w;
            }
        }
    }

    // ---- head: out = sigmoid( elu(h @ fc_w.T + fc_b) @ fc2_w.T + fc2_b ) ----
    // lane handles fc rows n and n+32
    float a0 = fc_b[n];
    float a1 = fc_b[n + 32];
    {
        const float4* f0 = reinterpret_cast<const float4*>(fc_w + n * 32);
        const float4* f1 = reinterpret_cast<const float4*>(fc_w + (n + 32) * 32);
#pragma unroll
        for (int q = 0; q < 8; ++q) {
            float4 v0 = f0[q];
            float4 v1 = f1[q];
            a0 = fmaf(v0.x, hreg[4 * q + 0], a0);
            a0 = fmaf(v0.y, hreg[4 * q + 1], a0);
            a0 = fmaf(v0.z, hreg[4 * q + 2], a0);
            a0 = fmaf(v0.w, hreg[4 * q + 3], a0);
            a1 = fmaf(v1.x, hreg[4 * q + 0], a1);
            a1 = fmaf(v1.y, hreg[4 * q + 1], a1);
            a1 = fmaf(v1.z, hreg[4 * q + 2], a1);
            a1 = fmaf(v1.w, hreg[4 * q + 3], a1);
        }
    }
    float partial = felu(a0) * fc2_w[n] + felu(a1) * fc2_w[n + 32];
#pragma unroll
    for (int m = 16; m >= 1; m >>= 1) partial += __shfl_xor(partial, m, 64);
    if (n == 0) out[b] = fsigmoid(partial + fc2_b[0]);
}

extern "C" void kernel_launch(void* const* d_in, const int* in_sizes, int n_in,
                              void* d_out, int out_size, void* d_ws, size_t ws_size,
                              hipStream_t stream) {
    const float* x       = (const float*)d_in[0];
    const int*   lengths = (const int*)d_in[1];
    const float* w_ih    = (const float*)d_in[2];
    const float* w_hh    = (const float*)d_in[3];
    const float* b_ih    = (const float*)d_in[4];
    const float* b_hh    = (const float*)d_in[5];
    const float* fc_w    = (const float*)d_in[6];
    const float* fc_b    = (const float*)d_in[7];
    const float* fc2_w   = (const float*)d_in[8];
    const float* fc2_b   = (const float*)d_in[9];
    float* out = (float*)d_out;

    int* perm = nullptr;
    if (ws_size >= (size_t)BB * sizeof(int)) {
        perm = (int*)d_ws;
        hipLaunchKernelGGL(sort_by_len_kernel, dim3(1), dim3(256), 0, stream, lengths, perm);
    }
    hipLaunchKernelGGL(lstm_kernel, dim3(BB / 2), dim3(64), 0, stream,
                       x, lengths, w_ih, w_hh, b_ih, b_hh,
                       fc_w, fc_b, fc2_w, fc2_b, out, perm);
}

// Round 2
// 686.581 us; speedup vs baseline: 1.3857x; 1.3857x over previous
//
#include <hip/hip_runtime.h>
#include <hip/hip_bf16.h>

constexpr int BB = 4096;   // batch
constexpr int TT = 2048;   // time
constexpr int HH = 32;     // hidden

typedef float v2f __attribute__((ext_vector_type(2)));
typedef float v4f __attribute__((ext_vector_type(4)));

// ---------- fast math (v_exp_f32 / v_rcp_f32) ----------
__device__ __forceinline__ float fexp2(float x) { return __builtin_amdgcn_exp2f(x); }
__device__ __forceinline__ float frcp(float x)  { return __builtin_amdgcn_rcpf(x); }
__device__ __forceinline__ float fsigmoid(float x) {
    return frcp(1.0f + fexp2(x * -1.4426950408889634f));
}
__device__ __forceinline__ float ftanh(float x) {
    return 1.0f - 2.0f * frcp(1.0f + fexp2(x * 2.8853900817779268f));
}
__device__ __forceinline__ float felu(float x) {
    return x > 0.0f ? x : (fexp2(x * 1.4426950408889634f) - 1.0f);
}

// ---------- kernel 1: counting sort of batch indices by length, descending ----------
__global__ void sort_by_len_kernel(const int* __restrict__ lengths, int* __restrict__ perm) {
    __shared__ int hist[TT];     // key = TT - len  in [0, TT-1]
    __shared__ int csum[256];
    const int tid = threadIdx.x;
    for (int i = tid; i < TT; i += 256) hist[i] = 0;
    __syncthreads();
    for (int i = tid; i < BB; i += 256) atomicAdd(&hist[TT - lengths[i]], 1);
    __syncthreads();
    const int base = tid * 8;
    int loc[8];
    int s = 0;
#pragma unroll
    for (int j = 0; j < 8; ++j) { loc[j] = hist[base + j]; s += loc[j]; }
    csum[tid] = s;
    __syncthreads();
    for (int off = 1; off < 256; off <<= 1) {
        int v = (tid >= off) ? csum[tid - off] : 0;
        __syncthreads();
        csum[tid] += v;
        __syncthreads();
    }
    int run = csum[tid] - s;
#pragma unroll
    for (int j = 0; j < 8; ++j) { int t = loc[j]; hist[base + j] = run; run += t; }
    __syncthreads();
    for (int i = tid; i < BB; i += 256) {
        int pos = atomicAdd(&hist[TT - lengths[i]], 1);
        perm[pos] = i;
    }
}

// ---------- kernel 2: backward LSTM + MLP head ----------
// 1 wave per block, 1 batch element per wave. Lane owns gate rows:
//   r0 = lane        (rows 0..63   = i-gates then f-gates)
//   r1 = lane + 64   (rows 64..127 = g-gates then o-gates)
// Weights: 2 rows x 32 = 64 floats/lane in VGPRs (v2f x16 each).
// Gate matvec uses v_pk_fma_f32 (packed fp32, 2 FLOP/lane/instr).
// h broadcast: ds_write_b32 + 8x same-address ds_read_b128 (pure broadcast).
__global__ __launch_bounds__(64, 3)
void lstm_kernel(const float* __restrict__ x, const int* __restrict__ lengths,
                 const float* __restrict__ w_ih, const float* __restrict__ w_hh,
                 const float* __restrict__ b_ih, const float* __restrict__ b_hh,
                 const float* __restrict__ fc_w, const float* __restrict__ fc_b,
                 const float* __restrict__ fc2_w, const float* __restrict__ fc2_b,
                 float* __restrict__ out, const int* __restrict__ perm) {
    __shared__ __align__(16) float hbuf[64];   // only [0..31] read; [32..63] = junk pad
    __shared__ float xbuf[64];

    const int lane = threadIdx.x;       // 0..63
    const int b = perm ? perm[blockIdx.x] : blockIdx.x;
    const int L = lengths[b];

    const int r0 = lane;        // i (lane<32) / f (lane>=32) row
    const int r1 = lane + 64;   // g (lane<32) / o (lane>=32) row

    // per-lane weights in registers
    v2f w0[16], w1[16];
    {
        const v2f* p0 = reinterpret_cast<const v2f*>(w_hh + r0 * 32);
        const v2f* p1 = reinterpret_cast<const v2f*>(w_hh + r1 * 32);
#pragma unroll
        for (int q = 0; q < 16; ++q) { w0[q] = p0[q]; w1[q] = p1[q]; }
    }
    const float wi0 = w_ih[r0];
    const float wi1 = w_ih[r1];
    const float bi0 = b_ih[r0] + b_hh[r0];
    const float bi1 = b_ih[r1] + b_hh[r1];

    // unified activation for acc1: lower half -> tanh(g) = 2*sigm(2g)-1; upper -> sigm(o)
    const bool  lower = lane < 32;
    const float kmul  = lower ? -2.8853900817779268f : -1.4426950408889634f;
    const float amul  = lower ? 2.0f : 1.0f;
    const float badd  = lower ? -1.0f : 0.0f;

    v2f h2[16];
#pragma unroll
    for (int q = 0; q < 16; ++q) h2[q] = (v2f){0.0f, 0.0f};
    float c = 0.0f;
    const float* xb = x + (size_t)b * TT;

    int t = L - 1;
    while (t >= 0) {
        const int tb = t & ~63;
        __syncthreads();
        xbuf[lane] = xb[tb + lane];    // tb+63 <= 2047 always in-bounds
        __syncthreads();
        for (; t >= tb; --t) {
            const float xt = xbuf[t - tb];
            v2f a0 = (v2f){0.0f, 0.0f};
            v2f a1 = (v2f){0.0f, 0.0f};
#pragma unroll
            for (int q = 0; q < 16; ++q) {
                a0 = __builtin_elementwise_fma(w0[q], h2[q], a0);
                a1 = __builtin_elementwise_fma(w1[q], h2[q], a1);
            }
            const float g0 = (a0.x + a0.y) + fmaf(wi0, xt, bi0);
            const float g1 = (a1.x + a1.y) + fmaf(wi1, xt, bi1);
            // acc0 is sigmoid for all lanes: i (lower) / f (upper)
            const float s0 = frcp(1.0f + fexp2(g0 * -1.4426950408889634f));
            // acc1: tanh(g) lower / sigmoid(o) upper
            const float s1 = frcp(1.0f + fexp2(g1 * kmul));
            const float v1 = fmaf(amul, s1, badd);
            // lower lanes need f (partner s0) and o (partner v1)
            const float fg = __shfl_xor(s0, 32);
            const float og = __shfl_xor(v1, 32);
            // lower lanes: i=s0, g=v1 ; c,h only meaningful there (upper lanes junk)
            c = fmaf(fg, c, s0 * v1);
            const float hn = og * ftanh(c);
            hbuf[lane] = hn;           // upper 32 write to pad region, never read
            __syncthreads();
            const v4f* hp = reinterpret_cast<const v4f*>(hbuf);
#pragma unroll
            for (int q = 0; q < 8; ++q) {
                v4f r = hp[q];                 // same-address broadcast read
                h2[2 * q]     = r.xy;
                h2[2 * q + 1] = r.zw;
            }
        }
    }

    // ---- head: out[b] = sigmoid( sum_r fc2_w[r]*elu(fc_w[r]@h + fc_b[r]) + fc2_b ) ----
    float a = fc_b[lane];
    {
        const v2f* fp = reinterpret_cast<const v2f*>(fc_w + lane * 32);
        v2f fa = (v2f){0.0f, 0.0f};
#pragma unroll
        for (int q = 0; q < 16; ++q) fa = __builtin_elementwise_fma(fp[q], h2[q], fa);
        a += fa.x + fa.y;
    }
    float partial = felu(a) * fc2_w[lane];
#pragma unroll
    for (int m = 32; m >= 1; m >>= 1) partial += __shfl_xor(partial, m, 64);
    if (lane == 0) out[b] = fsigmoid(partial + fc2_b[0]);
}

extern "C" void kernel_launch(void* const* d_in, const int* in_sizes, int n_in,
                              void* d_out, int out_size, void* d_ws, size_t ws_size,
                              hipStream_t stream) {
    const float* x       = (const float*)d_in[0];
    const int*   lengths = (const int*)d_in[1];
    const float* w_ih    = (const float*)d_in[2];
    const float* w_hh    = (const float*)d_in[3];
    const float* b_ih    = (const float*)d_in[4];
    const float* b_hh    = (const float*)d_in[5];
    const float* fc_w    = (const float*)d_in[6];
    const float* fc_b    = (const float*)d_in[7];
    const float* fc2_w   = (const float*)d_in[8];
    const float* fc2_b   = (const float*)d_in[9];
    float* out = (float*)d_out;

    int* perm = nullptr;
    if (ws_size >= (size_t)BB * sizeof(int)) {
        perm = (int*)d_ws;
        hipLaunchKernelGGL(sort_by_len_kernel, dim3(1), dim3(256), 0, stream, lengths, perm);
    }
    hipLaunchKernelGGL(lstm_kernel, dim3(BB), dim3(64), 0, stream,
                       x, lengths, w_ih, w_hh, b_ih, b_hh,
                       fc_w, fc_b, fc2_w, fc2_b, out, perm);
}